// Round 17
// baseline (190.105 us; speedup 1.0000x reference)
//
#include <hip/hip_runtime.h>
#include <cfloat>

#define NFEAT 256
#define BATCH 4096
#define MTOT  16384
#define NSTRIP 16
#define STRIPW 1024
#define NH 32                 // 32-col chunks per strip
#define UMARGIN 0.75f

typedef __attribute__((ext_vector_type(8))) short bf16x8;
typedef __attribute__((ext_vector_type(4))) float f32x4;

#define GP(p)   ((const __attribute__((address_space(1))) void*)(p))
#define LDSP(p) ((__attribute__((address_space(3))) void*)(p))

__device__ __forceinline__ unsigned bf16pack(float a, float b) {
    unsigned ua = __float_as_uint(a), ub = __float_as_uint(b);
    unsigned ra = (ua + 0x7fffu + ((ua >> 16) & 1u)) >> 16;
    unsigned rb = (ub + 0x7fffu + ((ub >> 16) & 1u)) >> 16;
    return ra | (rb << 16);
}

// ---------------------------------------------------------------------------
// Prep (fused): fp32->bf16 + squared norm for both w and xb. 1 wave per row.
// (rounds 4-9 verified, absmax 0)
// ---------------------------------------------------------------------------
__global__ __launch_bounds__(256) void prep_kernel(const float* __restrict__ xb,
                                                   const float* __restrict__ w,
                                                   uint2* __restrict__ Abf,
                                                   uint2* __restrict__ Bbf,
                                                   float* __restrict__ a2,
                                                   float* __restrict__ b2) {
    int gid  = blockIdx.x * blockDim.x + threadIdx.x;
    int row  = gid >> 6;
    int lane = gid & 63;
    const float* src;
    uint2* dst;
    float* nrm;
    if (row < MTOT) {
        src = w + (size_t)row * NFEAT;  dst = Bbf + (size_t)row * 64;  nrm = b2 + row;
    } else {
        int r = row - MTOT;
        src = xb + (size_t)r * NFEAT;   dst = Abf + (size_t)r * 64;    nrm = a2 + r;
    }
    float4 v = ((const float4*)src)[lane];
    dst[lane] = make_uint2(bf16pack(v.x, v.y), bf16pack(v.z, v.w));
    float s = v.x * v.x + v.y * v.y + v.z * v.z + v.w * v.w;
    #pragma unroll
    for (int off = 32; off > 0; off >>= 1) s += __shfl_down(s, off);
    if (lane == 0) *nrm = s;
}

// ---------------------------------------------------------------------------
// Main: round-10's 48.7 us core (3-deep ring, one barrier/chunk, bf16 A from
// Abf) + FUSED refine tail. After a block publishes its part slice (agent-
// scope stores + threadfence), it bumps cnt[mtile] (device-scope atomic);
// the 16th arriver refines all 128 rows of the m-tile in-kernel (agent-scope
// loads; deterministic result regardless of which block runs it).
// Grid 512 = 32 m-tiles x 16 strips (2 strips/XCD); 4 waves x (32 rows x
// 32 cols); afr[2][8]=64 VGPR pinned; LDS 3x16K ring + b2 4K (2 blocks/CU).
// Per chunk h: vmcnt(4) -> barrier -> stage(h+2) -> 16 ds_read + 32 MFMA
// (setprio) -> top-2 fold (6-bit mantissa id). Read swizzle ^((col&7)<<4),
// inverse pre-applied to the staging source. min-dist == max-(dot - b2/2).
// ---------------------------------------------------------------------------
__global__ __launch_bounds__(256, 2) void som_core(
        const unsigned short* __restrict__ Abf, const unsigned short* __restrict__ Bbf,
        const float* __restrict__ b2, const float* __restrict__ xb,
        const float* __restrict__ w, const float* __restrict__ a2,
        unsigned long long* __restrict__ part, int* __restrict__ cnt,
        int* __restrict__ out) {
    __shared__ char smem[53248];    // ring 3 x 16K | b2 strip 4K

    const int t = threadIdx.x, l = t & 63;
    const int wid = t >> 6;                    // wave = 32-row band
    const int x = blockIdx.x & 7, y = blockIdx.x >> 3;
    const int strip = x * 2 + (y >> 5);        // 2 strips per XCD
    const int mtile = y & 31;
    const int m0 = mtile * 128;
    const int ns0 = strip * STRIPW;

    // ---- A panel -> 64 VGPRs (frag layout, bf16 from Abf), pinned ----
    const char* gA = (const char*)Abf
                   + (size_t)(m0 + wid * 32 + (l & 15)) * 512 + (l >> 4) * 16;
    bf16x8 afr[2][8];
    #pragma unroll
    for (int mf = 0; mf < 2; ++mf)
        #pragma unroll
        for (int kk = 0; kk < 8; ++kk)
            afr[mf][kk] = *(const bf16x8*)(gA + (size_t)mf * 16 * 512 + kk * 64);

    // ---- staging: chunk = 32 cols x 512 B = 16 KB = 4 ops/thread ----
    const int sbyte = ((t & 31) * 16) ^ ((t >> 5) << 4);
    const char* gBs = (const char*)Bbf + (size_t)(ns0 + (t >> 5)) * 512 + sbyte;
#define STAGE(dstb, c) {                                                         \
        const char* s_ = gBs + (size_t)(c) * 16384;                              \
        char* d_ = (dstb) + t * 16;                                              \
        __builtin_amdgcn_global_load_lds(GP(s_),         LDSP(d_),         16,0,0); \
        __builtin_amdgcn_global_load_lds(GP(s_ + 4096),  LDSP(d_ + 4096),  16,0,0); \
        __builtin_amdgcn_global_load_lds(GP(s_ + 8192),  LDSP(d_ + 8192),  16,0,0); \
        __builtin_amdgcn_global_load_lds(GP(s_ + 12288), LDSP(d_ + 12288), 16,0,0); }

    __builtin_amdgcn_global_load_lds(GP((const char*)b2 + (size_t)ns0 * 4 + t * 16),
                                     LDSP(smem + 49152 + t * 16), 16, 0, 0);
    STAGE(smem,         0)
    STAGE(smem + 16384, 1)

    #pragma unroll
    for (int mf = 0; mf < 2; ++mf)
        #pragma unroll
        for (int kk = 0; kk < 8; ++kk)
            asm volatile("" : "+v"(afr[mf][kk]));

    float r0[2][4], r1[2][4];
    #pragma unroll
    for (int mf = 0; mf < 2; ++mf)
        #pragma unroll
        for (int j = 0; j < 4; ++j) { r0[mf][j] = -FLT_MAX; r1[mf][j] = -FLT_MAX; }

    char* pr = smem;
    char* pm = smem + 16384;
    char* ps = smem + 32768;
    const int rswz = (l & 7) << 4;
    const int cb = (l & 15) * 512;

    for (int h = 0; h < NH; ++h) {
        if (h < NH - 1) asm volatile("s_waitcnt vmcnt(4)" ::: "memory");
        else            asm volatile("s_waitcnt vmcnt(0)" ::: "memory");
        __builtin_amdgcn_s_barrier();
        asm volatile("" ::: "memory");

        if (h + 2 < NH) STAGE(ps, h + 2)

        const int c0 = h * 32 + (l & 15);
        const float b20 = -0.5f * *(const float*)(smem + 49152 + c0 * 4);
        const float b21 = -0.5f * *(const float*)(smem + 49152 + c0 * 4 + 64);
        f32x4 acc[2][2];
        #pragma unroll
        for (int mf = 0; mf < 2; ++mf) {
            acc[mf][0] = (f32x4){b20, b20, b20, b20};
            acc[mf][1] = (f32x4){b21, b21, b21, b21};
        }

        __builtin_amdgcn_s_setprio(1);
        #pragma unroll
        for (int kk = 0; kk < 8; ++kk) {
            const int ko = (kk * 64 + (l >> 4) * 16) ^ rswz;
            bf16x8 bf0 = *(const bf16x8*)(pr + cb + ko);
            bf16x8 bf1 = *(const bf16x8*)(pr + 8192 + cb + ko);
            #pragma unroll
            for (int mf = 0; mf < 2; ++mf) {
                acc[mf][0] = __builtin_amdgcn_mfma_f32_16x16x32_bf16(afr[mf][kk], bf0, acc[mf][0], 0, 0, 0);
                acc[mf][1] = __builtin_amdgcn_mfma_f32_16x16x32_bf16(afr[mf][kk], bf1, acc[mf][1], 0, 0, 0);
            }
        }
        __builtin_amdgcn_s_setprio(0);

        #pragma unroll
        for (int nf = 0; nf < 2; ++nf) {
            const unsigned idn = (unsigned)(h * 2 + nf);
            #pragma unroll
            for (int mf = 0; mf < 2; ++mf)
                #pragma unroll
                for (int j = 0; j < 4; ++j) {
                    float p = __uint_as_float((__float_as_uint(acc[mf][nf][j]) & 0xFFFFFFC0u) | idn);
                    float nr1 = __builtin_amdgcn_fmed3f(r0[mf][j], r1[mf][j], p);
                    r0[mf][j] = fmaxf(r0[mf][j], p);
                    r1[mf][j] = nr1;
                }
        }

        char* tp = pr; pr = pm; pm = ps; ps = tp;
    }

    // ---- per-row merge over 16 lane-cols (10-bit repack); publish part ----
    #pragma unroll
    for (int mf = 0; mf < 2; ++mf)
        #pragma unroll
        for (int j = 0; j < 4; ++j) {
            unsigned u0 = __float_as_uint(r0[mf][j]);
            unsigned u1 = __float_as_uint(r1[mf][j]);
            u0 = (u0 & 0xFFFFFC00u) | ((u0 & 63u) << 4) | (unsigned)(l & 15);
            u1 = (u1 & 0xFFFFFC00u) | ((u1 & 63u) << 4) | (unsigned)(l & 15);
            float v0 = __uint_as_float(u0), v1 = __uint_as_float(u1);
            #pragma unroll
            for (int off = 1; off < 16; off <<= 1) {
                float o0 = __shfl_xor(v0, off), o1 = __shfl_xor(v1, off);
                float nv1 = fmaxf(fminf(v0, o0), fmaxf(v1, o1));
                v0 = fmaxf(v0, o0);
                v1 = nv1;
            }
            if ((l & 15) == 0) {
                int row = m0 + wid * 32 + mf * 16 + (l >> 4) * 4 + j;
                unsigned long long pv =
                    ((unsigned long long)__float_as_uint(v1) << 32) | __float_as_uint(v0);
                __hip_atomic_store(&part[(size_t)row * NSTRIP + strip], pv,
                                   __ATOMIC_RELAXED, __HIP_MEMORY_SCOPE_AGENT);
            }
        }

    // ---- completion handshake: 16th arriver refines this m-tile ----
    __syncthreads();
    __threadfence();
    if (t == 0) {
        int old = __hip_atomic_fetch_add(&cnt[mtile], 1, __ATOMIC_ACQ_REL,
                                         __HIP_MEMORY_SCOPE_AGENT);
        *(volatile int*)smem = old;
    }
    __syncthreads();
    if (*(volatile int*)smem != NSTRIP - 1) return;

    // ---- fused refine: 128 rows, 4 waves x 2 rows/pass x 16 passes.
    //      Lanes 0..31 / 32..63 each own one row; entry e = l&31 maps to
    //      part[row][e>>1] float-slot (e&1). Exact fp32+sqrt recompute of
    //      candidates within margin; lexicographic (dist, idx) argmin. ----
    for (int psn = 0; psn < 16; ++psn) {
        const int row = m0 + wid * 32 + psn * 2 + (l >> 5);
        const int e = l & 31;
        unsigned long long pu = __hip_atomic_load(
            &part[(size_t)row * NSTRIP + (e >> 1)],
            __ATOMIC_RELAXED, __HIP_MEMORY_SCOPE_AGENT);
        float v = __uint_as_float((unsigned)((e & 1) ? (pu >> 32) : (pu & 0xffffffffu)));
        float mx = v;
        #pragma unroll
        for (int off = 1; off < 32; off <<= 1) mx = fmaxf(mx, __shfl_xor(mx, off));
        const float cut = mx - UMARGIN;

        unsigned long long key = ~0ull;
        if (v >= cut) {
            unsigned b = __float_as_uint(v);
            int lane4 = b & 15, id6 = (b >> 4) & 63;
            int col = (e >> 1) * STRIPW + (id6 >> 1) * 32 + (id6 & 1) * 16 + lane4;
            const float4* xr = (const float4*)(xb + (size_t)row * NFEAT);
            const float4* wr = (const float4*)(w + (size_t)col * NFEAT);
            float s0 = 0.f, s1 = 0.f;
            #pragma unroll
            for (int k = 0; k < 32; ++k) {
                float4 x0 = xr[2 * k + 0], w0 = wr[2 * k + 0];
                float4 x1 = xr[2 * k + 1], w1 = wr[2 * k + 1];
                s0 += x0.x * w0.x + x0.y * w0.y + x0.z * w0.z + x0.w * w0.w;
                s1 += x1.x * w1.x + x1.y * w1.y + x1.z * w1.z + x1.w * w1.w;
            }
            float dd = a2[row] + b2[col] - 2.f * (s0 + s1);
            float s = sqrtf(fmaxf(dd, 0.f));
            key = ((unsigned long long)__float_as_uint(s) << 32) | (unsigned)col;
        }
        #pragma unroll
        for (int off = 1; off < 32; off <<= 1) {
            unsigned long long o = __shfl_xor(key, off);
            key = o < key ? o : key;
        }
        if (e == 0) {
            int idx = (int)(key & 0xffffffffu);
            out[2 * row]     = idx >> 7;
            out[2 * row + 1] = idx & 127;
        }
    }
#undef STAGE
}

extern "C" void kernel_launch(void* const* d_in, const int* in_sizes, int n_in,
                              void* d_out, int out_size, void* d_ws, size_t ws_size,
                              hipStream_t stream) {
    const float* xb = (const float*)d_in[0];   // (4096, 256)
    const float* w  = (const float*)d_in[1];   // (16384, 256)
    int* out = (int*)d_out;

    char* ws = (char*)d_ws;
    unsigned short* Abf = (unsigned short*)ws;                       // 2 MB
    unsigned short* Bbf = (unsigned short*)(ws + (2u << 20));        // 8 MB
    float* a2 = (float*)(ws + (10u << 20));                          // 16 KB
    float* b2 = (float*)(ws + (10u << 20) + (64u << 10));            // 64 KB
    unsigned long long* part =
        (unsigned long long*)(ws + (10u << 20) + (128u << 10));      // 512 KB
    int* cnt = (int*)(ws + (11u << 20));                             // 128 B

    hipMemsetAsync(cnt, 0, 32 * sizeof(int), stream);
    prep_kernel<<<((MTOT + BATCH) * 64) / 256, 256, 0, stream>>>(xb, w, (uint2*)Abf,
                                                                 (uint2*)Bbf, a2, b2);
    som_core<<<512, 256, 0, stream>>>(Abf, Bbf, b2, xb, w, a2, part, cnt, out);
}

// Round 18
// 154.147 us; speedup vs baseline: 1.2333x; 1.2333x over previous
//
#include <hip/hip_runtime.h>
#include <cfloat>

#define NFEAT 256
#define BATCH 4096
#define MTOT  16384
#define NSTRIP 16
#define STRIPW 1024
#define NH 32                 // 32-col chunks per strip
#define UMARGIN 0.75f

typedef __attribute__((ext_vector_type(8))) short bf16x8;
typedef __attribute__((ext_vector_type(4))) float f32x4;

#define GP(p)   ((const __attribute__((address_space(1))) void*)(p))
#define LDSP(p) ((__attribute__((address_space(3))) void*)(p))

__device__ __forceinline__ unsigned bf16pack(float a, float b) {
    unsigned ua = __float_as_uint(a), ub = __float_as_uint(b);
    unsigned ra = (ua + 0x7fffu + ((ua >> 16) & 1u)) >> 16;
    unsigned rb = (ub + 0x7fffu + ((ub >> 16) & 1u)) >> 16;
    return ra | (rb << 16);
}

// ---------------------------------------------------------------------------
// Prep (fused): fp32->bf16 + squared norm for both w and xb. 1 wave per row.
// ---------------------------------------------------------------------------
__global__ __launch_bounds__(256) void prep_kernel(const float* __restrict__ xb,
                                                   const float* __restrict__ w,
                                                   uint2* __restrict__ Abf,
                                                   uint2* __restrict__ Bbf,
                                                   float* __restrict__ a2,
                                                   float* __restrict__ b2) {
    int gid  = blockIdx.x * blockDim.x + threadIdx.x;
    int row  = gid >> 6;
    int lane = gid & 63;
    const float* src;
    uint2* dst;
    float* nrm;
    if (row < MTOT) {
        src = w + (size_t)row * NFEAT;  dst = Bbf + (size_t)row * 64;  nrm = b2 + row;
    } else {
        int r = row - MTOT;
        src = xb + (size_t)r * NFEAT;   dst = Abf + (size_t)r * 64;    nrm = a2 + r;
    }
    float4 v = ((const float4*)src)[lane];
    dst[lane] = make_uint2(bf16pack(v.x, v.y), bf16pack(v.z, v.w));
    float s = v.x * v.x + v.y * v.y + v.z * v.z + v.w * v.w;
    #pragma unroll
    for (int off = 32; off > 0; off >>= 1) s += __shfl_down(s, off);
    if (lane == 0) *nrm = s;
}

// ---------------------------------------------------------------------------
// Main: round-10 core (3-deep ring, one barrier/chunk, bf16 A) + fused refine
// tail. ROUND-17 LESSON: acq_rel/threadfence emit buffer_wbl2 + buffer_inv
// (L2 flush/invalidate) per block -> co-resident blocks' B-stream goes cold
// (MfmaUtil 27->7). This version uses ONLY relaxed agent-scope atomics
// (sc-flag coherent-point access, NO cache maintenance). Ordering: the HIP
// compiler drains vmcnt(0) before s_barrier, so after __syncthreads every
// wave's part-stores are globally visible before t0's counter RMW; the
// refiner's part-loads are control-dependent on the RMW result.
// ---------------------------------------------------------------------------
__global__ __launch_bounds__(256, 2) void som_core(
        const unsigned short* __restrict__ Abf, const unsigned short* __restrict__ Bbf,
        const float* __restrict__ b2, const float* __restrict__ xb,
        const float* __restrict__ w, const float* __restrict__ a2,
        unsigned long long* __restrict__ part, int* __restrict__ cnt,
        int* __restrict__ out) {
    __shared__ char smem[53248];    // ring 3 x 16K | b2 strip 4K

    const int t = threadIdx.x, l = t & 63;
    const int wid = t >> 6;                    // wave = 32-row band
    const int x = blockIdx.x & 7, y = blockIdx.x >> 3;
    const int strip = x * 2 + (y >> 5);        // 2 strips per XCD
    const int mtile = y & 31;
    const int m0 = mtile * 128;
    const int ns0 = strip * STRIPW;

    // ---- A panel -> 64 VGPRs (frag layout, bf16 from Abf), pinned ----
    const char* gA = (const char*)Abf
                   + (size_t)(m0 + wid * 32 + (l & 15)) * 512 + (l >> 4) * 16;
    bf16x8 afr[2][8];
    #pragma unroll
    for (int mf = 0; mf < 2; ++mf)
        #pragma unroll
        for (int kk = 0; kk < 8; ++kk)
            afr[mf][kk] = *(const bf16x8*)(gA + (size_t)mf * 16 * 512 + kk * 64);

    // ---- staging: chunk = 32 cols x 512 B = 16 KB = 4 ops/thread ----
    const int sbyte = ((t & 31) * 16) ^ ((t >> 5) << 4);
    const char* gBs = (const char*)Bbf + (size_t)(ns0 + (t >> 5)) * 512 + sbyte;
#define STAGE(dstb, c) {                                                         \
        const char* s_ = gBs + (size_t)(c) * 16384;                              \
        char* d_ = (dstb) + t * 16;                                              \
        __builtin_amdgcn_global_load_lds(GP(s_),         LDSP(d_),         16,0,0); \
        __builtin_amdgcn_global_load_lds(GP(s_ + 4096),  LDSP(d_ + 4096),  16,0,0); \
        __builtin_amdgcn_global_load_lds(GP(s_ + 8192),  LDSP(d_ + 8192),  16,0,0); \
        __builtin_amdgcn_global_load_lds(GP(s_ + 12288), LDSP(d_ + 12288), 16,0,0); }

    __builtin_amdgcn_global_load_lds(GP((const char*)b2 + (size_t)ns0 * 4 + t * 16),
                                     LDSP(smem + 49152 + t * 16), 16, 0, 0);
    STAGE(smem,         0)
    STAGE(smem + 16384, 1)

    #pragma unroll
    for (int mf = 0; mf < 2; ++mf)
        #pragma unroll
        for (int kk = 0; kk < 8; ++kk)
            asm volatile("" : "+v"(afr[mf][kk]));

    float r0[2][4], r1[2][4];
    #pragma unroll
    for (int mf = 0; mf < 2; ++mf)
        #pragma unroll
        for (int j = 0; j < 4; ++j) { r0[mf][j] = -FLT_MAX; r1[mf][j] = -FLT_MAX; }

    char* pr = smem;
    char* pm = smem + 16384;
    char* ps = smem + 32768;
    const int rswz = (l & 7) << 4;
    const int cb = (l & 15) * 512;

    for (int h = 0; h < NH; ++h) {
        if (h < NH - 1) asm volatile("s_waitcnt vmcnt(4)" ::: "memory");
        else            asm volatile("s_waitcnt vmcnt(0)" ::: "memory");
        __builtin_amdgcn_s_barrier();
        asm volatile("" ::: "memory");

        if (h + 2 < NH) STAGE(ps, h + 2)

        const int c0 = h * 32 + (l & 15);
        const float b20 = -0.5f * *(const float*)(smem + 49152 + c0 * 4);
        const float b21 = -0.5f * *(const float*)(smem + 49152 + c0 * 4 + 64);
        f32x4 acc[2][2];
        #pragma unroll
        for (int mf = 0; mf < 2; ++mf) {
            acc[mf][0] = (f32x4){b20, b20, b20, b20};
            acc[mf][1] = (f32x4){b21, b21, b21, b21};
        }

        __builtin_amdgcn_s_setprio(1);
        #pragma unroll
        for (int kk = 0; kk < 8; ++kk) {
            const int ko = (kk * 64 + (l >> 4) * 16) ^ rswz;
            bf16x8 bf0 = *(const bf16x8*)(pr + cb + ko);
            bf16x8 bf1 = *(const bf16x8*)(pr + 8192 + cb + ko);
            #pragma unroll
            for (int mf = 0; mf < 2; ++mf) {
                acc[mf][0] = __builtin_amdgcn_mfma_f32_16x16x32_bf16(afr[mf][kk], bf0, acc[mf][0], 0, 0, 0);
                acc[mf][1] = __builtin_amdgcn_mfma_f32_16x16x32_bf16(afr[mf][kk], bf1, acc[mf][1], 0, 0, 0);
            }
        }
        __builtin_amdgcn_s_setprio(0);

        #pragma unroll
        for (int nf = 0; nf < 2; ++nf) {
            const unsigned idn = (unsigned)(h * 2 + nf);
            #pragma unroll
            for (int mf = 0; mf < 2; ++mf)
                #pragma unroll
                for (int j = 0; j < 4; ++j) {
                    float p = __uint_as_float((__float_as_uint(acc[mf][nf][j]) & 0xFFFFFFC0u) | idn);
                    float nr1 = __builtin_amdgcn_fmed3f(r0[mf][j], r1[mf][j], p);
                    r0[mf][j] = fmaxf(r0[mf][j], p);
                    r1[mf][j] = nr1;
                }
        }

        char* tp = pr; pr = pm; pm = ps; ps = tp;
    }

    // ---- per-row merge over 16 lane-cols (10-bit repack); publish part
    //      with RELAXED agent-scope atomic stores (coherent-point write,
    //      no cache maintenance) ----
    #pragma unroll
    for (int mf = 0; mf < 2; ++mf)
        #pragma unroll
        for (int j = 0; j < 4; ++j) {
            unsigned u0 = __float_as_uint(r0[mf][j]);
            unsigned u1 = __float_as_uint(r1[mf][j]);
            u0 = (u0 & 0xFFFFFC00u) | ((u0 & 63u) << 4) | (unsigned)(l & 15);
            u1 = (u1 & 0xFFFFFC00u) | ((u1 & 63u) << 4) | (unsigned)(l & 15);
            float v0 = __uint_as_float(u0), v1 = __uint_as_float(u1);
            #pragma unroll
            for (int off = 1; off < 16; off <<= 1) {
                float o0 = __shfl_xor(v0, off), o1 = __shfl_xor(v1, off);
                float nv1 = fmaxf(fminf(v0, o0), fmaxf(v1, o1));
                v0 = fmaxf(v0, o0);
                v1 = nv1;
            }
            if ((l & 15) == 0) {
                int row = m0 + wid * 32 + mf * 16 + (l >> 4) * 4 + j;
                unsigned long long pv =
                    ((unsigned long long)__float_as_uint(v1) << 32) | __float_as_uint(v0);
                __hip_atomic_store(&part[(size_t)row * NSTRIP + strip], pv,
                                   __ATOMIC_RELAXED, __HIP_MEMORY_SCOPE_AGENT);
            }
        }

    // ---- completion handshake (NO fence, NO acq_rel): __syncthreads drains
    //      vmcnt(0) per wave (compiler-guaranteed), so all part stores are
    //      at the coherent point before t0's relaxed RMW issues. ----
    __syncthreads();
    if (t == 0) {
        int old = __hip_atomic_fetch_add(&cnt[mtile], 1, __ATOMIC_RELAXED,
                                         __HIP_MEMORY_SCOPE_AGENT);
        *(volatile int*)smem = old;
    }
    __syncthreads();
    if (*(volatile int*)smem != NSTRIP - 1) return;

    // ---- fused refine: 128 rows, 4 waves x 2 rows/pass x 16 passes.
    //      Relaxed agent loads (bypass stale caches); loads are control-
    //      dependent on the RMW result. Exact fp32+sqrt recompute within
    //      margin; lexicographic (dist, idx) argmin. ----
    for (int psn = 0; psn < 16; ++psn) {
        const int row = m0 + wid * 32 + psn * 2 + (l >> 5);
        const int e = l & 31;
        unsigned long long pu = __hip_atomic_load(
            &part[(size_t)row * NSTRIP + (e >> 1)],
            __ATOMIC_RELAXED, __HIP_MEMORY_SCOPE_AGENT);
        float v = __uint_as_float((unsigned)((e & 1) ? (pu >> 32) : (pu & 0xffffffffu)));
        float mx = v;
        #pragma unroll
        for (int off = 1; off < 32; off <<= 1) mx = fmaxf(mx, __shfl_xor(mx, off));
        const float cut = mx - UMARGIN;

        unsigned long long key = ~0ull;
        if (v >= cut) {
            unsigned b = __float_as_uint(v);
            int lane4 = b & 15, id6 = (b >> 4) & 63;
            int col = (e >> 1) * STRIPW + (id6 >> 1) * 32 + (id6 & 1) * 16 + lane4;
            const float4* xr = (const float4*)(xb + (size_t)row * NFEAT);
            const float4* wr = (const float4*)(w + (size_t)col * NFEAT);
            float s0 = 0.f, s1 = 0.f;
            #pragma unroll
            for (int k = 0; k < 32; ++k) {
                float4 x0 = xr[2 * k + 0], w0 = wr[2 * k + 0];
                float4 x1 = xr[2 * k + 1], w1 = wr[2 * k + 1];
                s0 += x0.x * w0.x + x0.y * w0.y + x0.z * w0.z + x0.w * w0.w;
                s1 += x1.x * w1.x + x1.y * w1.y + x1.z * w1.z + x1.w * w1.w;
            }
            float dd = a2[row] + b2[col] - 2.f * (s0 + s1);
            float s = sqrtf(fmaxf(dd, 0.f));
            key = ((unsigned long long)__float_as_uint(s) << 32) | (unsigned)col;
        }
        #pragma unroll
        for (int off = 1; off < 32; off <<= 1) {
            unsigned long long o = __shfl_xor(key, off);
            key = o < key ? o : key;
        }
        if (e == 0) {
            int idx = (int)(key & 0xffffffffu);
            out[2 * row]     = idx >> 7;
            out[2 * row + 1] = idx & 127;
        }
    }
#undef STAGE
}

extern "C" void kernel_launch(void* const* d_in, const int* in_sizes, int n_in,
                              void* d_out, int out_size, void* d_ws, size_t ws_size,
                              hipStream_t stream) {
    const float* xb = (const float*)d_in[0];   // (4096, 256)
    const float* w  = (const float*)d_in[1];   // (16384, 256)
    int* out = (int*)d_out;

    char* ws = (char*)d_ws;
    unsigned short* Abf = (unsigned short*)ws;                       // 2 MB
    unsigned short* Bbf = (unsigned short*)(ws + (2u << 20));        // 8 MB
    float* a2 = (float*)(ws + (10u << 20));                          // 16 KB
    float* b2 = (float*)(ws + (10u << 20) + (64u << 10));            // 64 KB
    unsigned long long* part =
        (unsigned long long*)(ws + (10u << 20) + (128u << 10));      // 512 KB
    int* cnt = (int*)(ws + (11u << 20));                             // 128 B

    hipMemsetAsync(cnt, 0, 32 * sizeof(int), stream);
    prep_kernel<<<((MTOT + BATCH) * 64) / 256, 256, 0, stream>>>(xb, w, (uint2*)Abf,
                                                                 (uint2*)Bbf, a2, b2);
    som_core<<<512, 256, 0, stream>>>(Abf, Bbf, b2, xb, w, a2, part, cnt, out);
}